// Round 12
// baseline (526.452 us; speedup 1.0000x reference)
//
#include <hip/hip_runtime.h>
#include <hip/hip_bf16.h>
#include <hip/hip_fp16.h>

#define N_NODES 128000
#define E_EDGES 2048000
#define G_GRAPHS 512
#define D_IN 12
#define D_H 64
#define N_CLS 10
#define BN_EPS 1e-5f
#define NB 1000        // buckets = dst >> 7 (128-node ranges)
#define BCAP 2560      // fixed records per bucket region (mean 2048, sd 45 -> 11 sigma)
#define TILE 8192      // edges per k_bin block (250 blocks)
#define NPW 8          // nodes per wave (amortize prologue + W-stage)

typedef _Float16 h2vec __attribute__((ext_vector_type(2)));
typedef _Float16 h4vec __attribute__((ext_vector_type(4)));

// ---------------- CSR build: bucket counting-sort ----------------

__global__ __launch_bounds__(256) void k_bin(const int* __restrict__ src, const int* __restrict__ dst,
                                             const float2* __restrict__ attr, int* __restrict__ gcount,
                                             int2* __restrict__ stage) {
    __shared__ int hist[NB];
    __shared__ int base_s[NB];
    __shared__ int rk[TILE];  // packed b(10)<<20 | dstLow(7)<<13 | rank(13)
    const int t = threadIdx.x;
    const int e0 = blockIdx.x * TILE;
    for (int i = t; i < NB; i += 256) hist[i] = 0;
    __syncthreads();
    for (int i = t; i < TILE; i += 256) {
        int d = dst[e0 + i];
        int b = d >> 7;
        int r = atomicAdd(&hist[b], 1);
        rk[i] = (b << 20) | ((d & 127) << 13) | r;
    }
    __syncthreads();
    for (int i = t; i < NB; i += 256) {
        int cb = hist[i];
        base_s[i] = i * BCAP + ((cb > 0) ? atomicAdd(&gcount[i], cb) : 0);
    }
    __syncthreads();
    for (int i = t; i < TILE; i += 256) {
        int pr = rk[i];
        int b = pr >> 20, dl = (pr >> 13) & 127, r = pr & 8191;
        float2 a = attr[e0 + i];
        __half2 h2 = __floats2half2_rn(a.x, a.y);
        stage[base_s[b] + r] = make_int2(src[e0 + i] | (dl << 17), *(int*)&h2);
    }
}

__global__ __launch_bounds__(256) void k_bscan(const int* __restrict__ gcount, int* __restrict__ bbase,
                                               int* __restrict__ offsets) {
    __shared__ int sm[256];
    const int t = threadIdx.x;
    int c0 = gcount[t * 4], c1 = gcount[t * 4 + 1], c2 = gcount[t * 4 + 2], c3 = gcount[t * 4 + 3];
    int s = c0 + c1 + c2 + c3;
    sm[t] = s;
    __syncthreads();
    for (int off = 1; off < 256; off <<= 1) {
        int x = 0;
        if (t >= off) x = sm[t - off];
        __syncthreads();
        sm[t] += x;
        __syncthreads();
    }
    int base = sm[t] - s;  // exclusive
    if (t * 4 < NB)     bbase[t * 4]     = base;
    if (t * 4 + 1 < NB) bbase[t * 4 + 1] = base + c0;
    if (t * 4 + 2 < NB) bbase[t * 4 + 2] = base + c0 + c1;
    if (t * 4 + 3 < NB) bbase[t * 4 + 3] = base + c0 + c1 + c2;
    if (t == 255) offsets[N_NODES] = sm[255];
}

__global__ __launch_bounds__(256) void k_final(const int* __restrict__ gcount, const int* __restrict__ bbase,
                                               const int2* __restrict__ stage,
                                               int* __restrict__ offsets, int2* __restrict__ edges) {
    __shared__ int2 recs[BCAP];   // 20.5 KB
    __shared__ int cnt[128];
    __shared__ int excl[128];
    const int b = blockIdx.x, t = threadIdx.x;
    const int count = gcount[b];
    const int base = bbase[b];
    if (t < 128) cnt[t] = 0;
    __syncthreads();
    for (int i = t; i < count; i += 256) {
        int2 r = stage[b * BCAP + i];
        recs[i] = r;
        atomicAdd(&cnt[(r.x >> 17) & 127], 1);
    }
    __syncthreads();
    if (t == 0) {
        int s = 0;
        for (int k = 0; k < 128; ++k) { int c = cnt[k]; excl[k] = s; cnt[k] = s; s += c; }
    }
    __syncthreads();
    if (t < 128) offsets[b * 128 + t] = base + excl[t];
    for (int i = t; i < count; i += 256) {
        int2 r = recs[i];
        int dl = (r.x >> 17) & 127;
        int p = atomicAdd(&cnt[dl], 1);
        edges[base + p] = make_int2(r.x & 0x1FFFF, r.y);
    }
}

// pack x [N,12] fp32 -> [N,16] fp32 (channels 12..15 = 0): 64B rows = exactly 1 line
__global__ __launch_bounds__(256) void k_pack_x(const float* __restrict__ x, float* __restrict__ xp) {
    int idx = blockIdx.x * 256 + threadIdx.x;
    int n = idx >> 4, ch = idx & 15;
    xp[idx] = (ch < D_IN) ? x[n * D_IN + ch] : 0.f;
}

// ---------------- Layer 1 (12-dim input, 64-dim output, fp16 out) ----------------
// 16-burst unconditional gathers from 64B-aligned xp rows; NPW nodes per wave.
__global__ __launch_bounds__(256) void k_gine12(
    const float* __restrict__ x, const float* __restrict__ xp, __half* __restrict__ hout,
    const int* __restrict__ off, const int2* __restrict__ edges,
    const float* __restrict__ We1, const float* __restrict__ be1,
    const float* __restrict__ W1, const float* __restrict__ b1,
    const float* __restrict__ g1, const float* __restrict__ bt1,
    const float* __restrict__ rm1, const float* __restrict__ rv1,
    const float* __restrict__ Wr, const float* __restrict__ br) {
    __shared__ float W1lds[D_IN * 64];
    __shared__ float Wrlds[D_IN * 64];
    __shared__ float u_lds[4][D_IN];
    __shared__ float x_lds[4][D_IN];
    const int t = threadIdx.x, w = t >> 6, c = t & 63;
    const int c15 = c & 15;
    for (int i = t; i < D_IN * 64; i += 256) {
        W1lds[i] = W1[i];
        Wrlds[i] = Wr[i];
    }
    h2vec we2 = {(_Float16)0.f, (_Float16)0.f};
    float bec = 0.f;
    if (c < D_IN) { we2[0] = (_Float16)We1[c]; we2[1] = (_Float16)We1[D_IN + c]; bec = be1[c]; }
    const float sj = g1[c] * rsqrtf(rv1[c] + BN_EPS);
    const float cj = (b1[c] - rm1[c]) * sj + bt1[c];
    const float brj = br[c];
    __syncthreads();

    const int wbase = (blockIdx.x * 4 + w) * NPW;
    for (int nn = 0; nn < NPW; ++nn) {
        const int n = wbase + nn;
        const int rs = off[n], re = off[n + 1];
        float acc = 0.f;
        for (int base = rs; base < re; base += 64) {
            const int cnt = min(64, re - base);
            int2 rec = make_int2(0, 0);
            if (c < cnt) rec = edges[base + c];  // tail lanes hold (0,0) -> src 0 safe
            for (int j = 0; j < cnt; j += 16) {
                float hv[16];
                int pkv[16];
#pragma unroll
                for (int u = 0; u < 16; ++u) {
                    int s = __builtin_amdgcn_readlane(rec.x, j + u);
                    pkv[u] = __builtin_amdgcn_readlane(rec.y, j + u);
                    hv[u] = xp[(size_t)s * 16 + c15];  // unconditional, 1 line, 16 in flight
                }
#pragma unroll
                for (int u = 0; u < 16; ++u) {
                    if (j + u < cnt) {
                        float q = __builtin_amdgcn_fdot2(__builtin_bit_cast(h2vec, pkv[u]), we2, bec, false);
                        acc += fmaxf(hv[u] + q, 0.f);  // lanes c>=16 compute garbage, discarded below
                    }
                }
            }
        }
        if (c < D_IN) {
            float xc = x[(size_t)n * D_IN + c];
            x_lds[w][c] = xc;
            u_lds[w][c] = xc + acc;
        }
        float z = 0.f, r = 0.f;
#pragma unroll
        for (int k = 0; k < D_IN; ++k) {
            z = fmaf(u_lds[w][k], W1lds[k * 64 + c], z);
            r = fmaf(x_lds[w][k], Wrlds[k * 64 + c], r);
        }
        hout[(size_t)n * 64 + c] = __float2half(fmaxf(fmaf(z, sj, cj), 0.f) + r + brj);
    }
}

// ---------------- Layers 2/3 (64-dim, fp16 h storage) ----------------
// Packed-fp16 pair consume + fp16 dot2 epilogue; NPW nodes per wave.
__global__ __launch_bounds__(256) void k_gine64(
    const __half* __restrict__ hin, __half* __restrict__ hout,
    const int* __restrict__ off, const int2* __restrict__ edges,
    const float* __restrict__ We, const float* __restrict__ be,
    const float* __restrict__ W, const float* __restrict__ b,
    const float* __restrict__ g, const float* __restrict__ bt,
    const float* __restrict__ rm, const float* __restrict__ rv) {
    __shared__ _Float16 WtL[64][68];   // transposed W, fp16; 2-way aliasing is free (m136)
    __shared__ _Float16 uL[4][64];
    const int t = threadIdx.x, w = t >> 6, c = t & 63;
    for (int i = t; i < 4096; i += 256) {
        int k = i >> 6, cc = i & 63;
        WtL[cc][k] = (_Float16)W[i];   // W[k*64+cc]
    }
    const _Float16 we0h = (_Float16)We[c], we1h = (_Float16)We[64 + c];
    const h2vec we2f = {we0h, we1h};
    const h2vec we02 = {we0h, we0h};
    const h2vec we12 = {we1h, we1h};
    const float becf = be[c];
    const h2vec bec2 = {(_Float16)becf, (_Float16)becf};
    const h2vec zero2 = {(_Float16)0.f, (_Float16)0.f};
    const h2vec one2 = {(_Float16)1.f, (_Float16)1.f};
    const float sj = g[c] * rsqrtf(rv[c] + BN_EPS);
    const float cj = (b[c] - rm[c]) * sj + bt[c];
    const unsigned short* hin_us = (const unsigned short*)hin;
    __syncthreads();

    const int wbase = (blockIdx.x * 4 + w) * NPW;
    for (int nn = 0; nn < NPW; ++nn) {
        const int n = wbase + nn;
        const int rs = off[n], re = off[n + 1];
        const __half hc16 = hin[(size_t)n * 64 + c];
        float acc = 0.f;
        for (int base = rs; base < re; base += 64) {
            const int cnt = min(64, re - base);
            int2 rec = make_int2(0, 0);
            if (c < cnt) rec = edges[base + c];  // tail lanes hold (0,0) -> src 0 safe
            for (int j = 0; j < cnt; j += 16) {
                int hvr[16];
#pragma unroll
                for (int u = 0; u < 16; ++u) {
                    int s = __builtin_amdgcn_readlane(rec.x, j + u);
                    hvr[u] = hin_us[(size_t)s * 64 + c];  // 16 gathers in flight (zext ushort)
                }
#pragma unroll
                for (int p = 0; p < 8; ++p) {
                    const int e0 = j + 2 * p;
                    if (e0 + 1 < cnt) {
                        int pk0 = __builtin_amdgcn_readlane(rec.y, e0);
                        int pk1 = __builtin_amdgcn_readlane(rec.y, e0 + 1);
                        int axp = (pk1 << 16) | (pk0 & 0xffff);
                        int ayp = (pk1 & 0xffff0000) | ((unsigned)pk0 >> 16);
                        int h01 = (hvr[2 * p + 1] << 16) | hvr[2 * p];
                        h2vec q2 = __builtin_elementwise_fma(__builtin_bit_cast(h2vec, axp), we02, bec2);
                        q2 = __builtin_elementwise_fma(__builtin_bit_cast(h2vec, ayp), we12, q2);
                        h2vec m = __builtin_bit_cast(h2vec, h01) + q2;
                        m = __builtin_elementwise_max(m, zero2);
                        acc = __builtin_amdgcn_fdot2(m, one2, acc, false);
                    } else if (e0 < cnt) {
                        int pk0 = __builtin_amdgcn_readlane(rec.y, e0);
                        float q = __builtin_amdgcn_fdot2(__builtin_bit_cast(h2vec, pk0), we2f, becf, false);
                        __half hh = __ushort_as_half((unsigned short)hvr[2 * p]);
                        acc += fmaxf(__half2float(hh) + q, 0.f);
                    }
                }
            }
        }
        const float hc = __half2float(hc16);
        uL[w][c] = (_Float16)(hc + acc);
        float z = 0.f;
        const h4vec* u4p = (const h4vec*)uL[w];
        const h4vec* wt4p = (const h4vec*)&WtL[c][0];
#pragma unroll
        for (int k4 = 0; k4 < 16; ++k4) {
            h4vec uu = u4p[k4];
            h4vec ww = wt4p[k4];
            h2vec ul = __builtin_shufflevector(uu, uu, 0, 1);
            h2vec uh = __builtin_shufflevector(uu, uu, 2, 3);
            h2vec wl = __builtin_shufflevector(ww, ww, 0, 1);
            h2vec wh = __builtin_shufflevector(ww, ww, 2, 3);
            z = __builtin_amdgcn_fdot2(ul, wl, z, false);
            z = __builtin_amdgcn_fdot2(uh, wh, z, false);
        }
        hout[(size_t)n * 64 + c] = __float2half(fmaxf(fmaf(z, sj, cj), 0.f) + hc);
    }
}

// ---------------- Pool (mean+max per graph) + classifier ----------------
__global__ __launch_bounds__(256) void k_pool(
    const __half* __restrict__ h, const int* __restrict__ batch,
    const float* __restrict__ Wc1, const float* __restrict__ bc1,
    const float* __restrict__ Wc2, const float* __restrict__ bc2,
    float* __restrict__ out) {
    __shared__ float psum[4][64];
    __shared__ float pmax[4][64];
    __shared__ float pool[128];
    __shared__ float hid[64];
    const int t = threadIdx.x, w = t >> 6, c = t & 63;
    const int g = blockIdx.x;
    int lo = 0, hi = N_NODES;
    while (lo < hi) { int mid = (lo + hi) >> 1; if (batch[mid] < g) lo = mid + 1; else hi = mid; }
    int start = lo;
    hi = N_NODES;
    while (lo < hi) { int mid = (lo + hi) >> 1; if (batch[mid] < g + 1) lo = mid + 1; else hi = mid; }
    int end = lo;

    float s = 0.f, m = -3.4e38f;
    for (int i = start + w; i < end; i += 4) {
        float v = __half2float(h[(size_t)i * 64 + c]);
        s += v;
        m = fmaxf(m, v);
    }
    psum[w][c] = s;
    pmax[w][c] = m;
    __syncthreads();
    if (w == 0) {
        float ss = psum[0][c] + psum[1][c] + psum[2][c] + psum[3][c];
        float mm = fmaxf(fmaxf(pmax[0][c], pmax[1][c]), fmaxf(pmax[2][c], pmax[3][c]));
        int cnt = end - start;
        pool[c] = ss / fmaxf((float)cnt, 1.f);
        pool[64 + c] = (cnt > 0) ? mm : 0.f;
    }
    __syncthreads();
    if (t < 64) {
        float z = bc1[t];
#pragma unroll 8
        for (int k = 0; k < 128; ++k) z = fmaf(pool[k], Wc1[k * 64 + t], z);
        hid[t] = fmaxf(z, 0.f);
    }
    __syncthreads();
    if (t < N_CLS) {
        float z = bc2[t];
#pragma unroll
        for (int k = 0; k < 64; ++k) z = fmaf(hid[k], Wc2[k * N_CLS + t], z);
        out[g * N_CLS + t] = z;
    }
}

extern "C" void kernel_launch(void* const* d_in, const int* in_sizes, int n_in,
                              void* d_out, int out_size, void* d_ws, size_t ws_size,
                              hipStream_t stream) {
    const float* x     = (const float*)d_in[0];
    const int*   ei    = (const int*)d_in[1];
    const float* ea    = (const float*)d_in[2];
    const int*   batch = (const int*)d_in[3];
    const float* We1 = (const float*)d_in[4],  *be1 = (const float*)d_in[5];
    const float* We2 = (const float*)d_in[6],  *be2 = (const float*)d_in[7];
    const float* We3 = (const float*)d_in[8],  *be3 = (const float*)d_in[9];
    const float* W1 = (const float*)d_in[10], *b1 = (const float*)d_in[11];
    const float* g1 = (const float*)d_in[12], *bt1 = (const float*)d_in[13];
    const float* rm1 = (const float*)d_in[14], *rv1 = (const float*)d_in[15];
    const float* W2 = (const float*)d_in[16], *b2 = (const float*)d_in[17];
    const float* g2 = (const float*)d_in[18], *bt2 = (const float*)d_in[19];
    const float* rm2 = (const float*)d_in[20], *rv2 = (const float*)d_in[21];
    const float* W3 = (const float*)d_in[22], *b3 = (const float*)d_in[23];
    const float* g3 = (const float*)d_in[24], *bt3 = (const float*)d_in[25];
    const float* rm3 = (const float*)d_in[26], *rv3 = (const float*)d_in[27];
    const float* Wr = (const float*)d_in[28], *br = (const float*)d_in[29];
    const float* Wc1 = (const float*)d_in[30], *bc1 = (const float*)d_in[31];
    const float* Wc2 = (const float*)d_in[32], *bc2 = (const float*)d_in[33];

    int* off    = (int*)d_ws;                   // N+4
    int* gcount = off + (N_NODES + 4);          // 1024 (NB=1000, zero-padded)
    int* bbase  = gcount + 1024;                // 1024
    int2* edges = (int2*)(bbase + 1024);        // E * 8B packed records
    int2* stage = edges + E_EDGES;              // NB*BCAP * 8B fixed bucket regions
    __half* hA  = (__half*)(stage + (size_t)NB * BCAP);  // N*64 fp16
    __half* hB  = hA + (size_t)N_NODES * 64;    // N*64 fp16
    float* xp   = (float*)(hB + (size_t)N_NODES * 64);  // N*16 fp32 padded rows

    hipMemsetAsync(gcount, 0, 1024 * sizeof(int), stream);

    const int* src = ei;
    const int* dst = ei + E_EDGES;

    k_pack_x<<<N_NODES * 16 / 256, 256, 0, stream>>>(x, xp);
    k_bin<<<E_EDGES / TILE, 256, 0, stream>>>(src, dst, (const float2*)ea, gcount, stage);
    k_bscan<<<1, 256, 0, stream>>>(gcount, bbase, off);
    k_final<<<NB, 256, 0, stream>>>(gcount, bbase, stage, off, edges);

    const int gine_blocks = N_NODES / (4 * NPW);  // 4000: NPW nodes per wave, 4 waves/block
    k_gine12<<<gine_blocks, 256, 0, stream>>>(x, xp, hA, off, edges,
                                              We1, be1, W1, b1, g1, bt1, rm1, rv1, Wr, br);
    k_gine64<<<gine_blocks, 256, 0, stream>>>(hA, hB, off, edges,
                                              We2, be2, W2, b2, g2, bt2, rm2, rv2);
    k_gine64<<<gine_blocks, 256, 0, stream>>>(hB, hA, off, edges,
                                              We3, be3, W3, b3, g3, bt3, rm3, rv3);
    k_pool<<<G_GRAPHS, 256, 0, stream>>>(hA, batch, Wc1, bc1, Wc2, bc2, (float*)d_out);
}

// Round 13
// 517.128 us; speedup vs baseline: 1.0180x; 1.0180x over previous
//
#include <hip/hip_runtime.h>
#include <hip/hip_bf16.h>
#include <hip/hip_fp16.h>

#define N_NODES 128000
#define E_EDGES 2048000
#define G_GRAPHS 512
#define D_IN 12
#define D_H 64
#define N_CLS 10
#define BN_EPS 1e-5f
#define NB 1000        // buckets = dst >> 7 (128-node ranges)
#define BCAP 2560      // fixed records per bucket region
#define TILE 4096      // edges per k_bin block (500 blocks)
#define NPW 8          // nodes per wave in gine64

typedef _Float16 h2vec __attribute__((ext_vector_type(2)));
typedef _Float16 h4vec __attribute__((ext_vector_type(4)));

__device__ __forceinline__ float fp8_to_f32(int b) {
    return __builtin_amdgcn_cvt_f32_fp8(b, 0);
}
__device__ __forceinline__ unsigned char f32_to_fp8(float v) {
    return (unsigned char)(__builtin_amdgcn_cvt_pk_fp8_f32(v, v, 0, false) & 0xff);
}

// ---------------- CSR build: bucket counting-sort ----------------

__global__ __launch_bounds__(256) void k_bin(const int* __restrict__ src, const int* __restrict__ dst,
                                             const float2* __restrict__ attr, int* __restrict__ gcount,
                                             int2* __restrict__ stage) {
    __shared__ int hist[NB];
    __shared__ int base_s[NB];
    __shared__ int rk[TILE];  // packed b(10)<<20 | dstLow(7)<<13 | rank(13)
    const int t = threadIdx.x;
    const int e0 = blockIdx.x * TILE;
    for (int i = t; i < NB; i += 256) hist[i] = 0;
    __syncthreads();
    for (int i = t; i < TILE; i += 256) {
        int d = dst[e0 + i];
        int b = d >> 7;
        int r = atomicAdd(&hist[b], 1);
        rk[i] = (b << 20) | ((d & 127) << 13) | r;
    }
    __syncthreads();
    for (int i = t; i < NB; i += 256) {
        int cb = hist[i];
        base_s[i] = i * BCAP + ((cb > 0) ? atomicAdd(&gcount[i], cb) : 0);
    }
    __syncthreads();
    for (int i = t; i < TILE; i += 256) {
        int pr = rk[i];
        int b = pr >> 20, dl = (pr >> 13) & 127, r = pr & 8191;
        float2 a = attr[e0 + i];
        __half2 h2 = __floats2half2_rn(a.x, a.y);
        stage[base_s[b] + r] = make_int2(src[e0 + i] | (dl << 17), *(int*)&h2);
    }
}

__global__ __launch_bounds__(256) void k_bscan(const int* __restrict__ gcount, int* __restrict__ bbase,
                                               int* __restrict__ offsets) {
    __shared__ int sm[256];
    const int t = threadIdx.x;
    int c0 = gcount[t * 4], c1 = gcount[t * 4 + 1], c2 = gcount[t * 4 + 2], c3 = gcount[t * 4 + 3];
    int s = c0 + c1 + c2 + c3;
    sm[t] = s;
    __syncthreads();
    for (int off = 1; off < 256; off <<= 1) {
        int x = 0;
        if (t >= off) x = sm[t - off];
        __syncthreads();
        sm[t] += x;
        __syncthreads();
    }
    int base = sm[t] - s;  // exclusive
    if (t * 4 < NB)     bbase[t * 4]     = base;
    if (t * 4 + 1 < NB) bbase[t * 4 + 1] = base + c0;
    if (t * 4 + 2 < NB) bbase[t * 4 + 2] = base + c0 + c1;
    if (t * 4 + 3 < NB) bbase[t * 4 + 3] = base + c0 + c1 + c2;
    if (t == 255) offsets[N_NODES] = sm[255];
}

__global__ __launch_bounds__(256) void k_final(const int* __restrict__ gcount, const int* __restrict__ bbase,
                                               const int2* __restrict__ stage,
                                               int* __restrict__ offsets, int2* __restrict__ edges) {
    __shared__ int2 recs[BCAP];   // 20.5 KB
    __shared__ int cnt[128];
    __shared__ int incl[128];
    const int b = blockIdx.x, t = threadIdx.x;
    const int count = gcount[b];
    const int base = bbase[b];
    if (t < 128) cnt[t] = 0;
    __syncthreads();
    for (int i = t; i < count; i += 256) {
        int2 r = stage[b * BCAP + i];
        recs[i] = r;
        atomicAdd(&cnt[(r.x >> 17) & 127], 1);
    }
    __syncthreads();
    if (t < 128) incl[t] = cnt[t];
    __syncthreads();
    for (int off = 1; off < 128; off <<= 1) {   // parallel Hillis-Steele over 128
        int x = 0;
        if (t >= off && t < 128) x = incl[t - off];
        __syncthreads();
        if (t < 128) incl[t] += x;
        __syncthreads();
    }
    if (t < 128) {
        int ex = incl[t] - cnt[t];
        offsets[b * 128 + t] = base + ex;
        cnt[t] = ex;   // own slot only; becomes the placement cursor
    }
    __syncthreads();
    for (int i = t; i < count; i += 256) {
        int2 r = recs[i];
        int dl = (r.x >> 17) & 127;
        int p = atomicAdd(&cnt[dl], 1);
        edges[base + p] = make_int2(r.x & 0x1FFFF, r.y);
    }
}

// pack x [N,12] fp32 -> [N,16] fp16 (channels 12..15 = 0): 32B rows = 1 line/edge
__global__ __launch_bounds__(256) void k_pack_x(const float* __restrict__ x, __half* __restrict__ x16) {
    int idx = blockIdx.x * 256 + threadIdx.x;
    int n = idx >> 4, ch = idx & 15;
    x16[idx] = __float2half((ch < D_IN) ? x[n * D_IN + ch] : 0.f);
}

// ---------------- Layer 1 (12-dim input, 64-dim output; fp16+fp8 out) ----------------
__global__ __launch_bounds__(256) void k_gine12(
    const float* __restrict__ x, const __half* __restrict__ x16,
    __half* __restrict__ hout, unsigned char* __restrict__ hout8,
    const int* __restrict__ off, const int2* __restrict__ edges,
    const float* __restrict__ We1, const float* __restrict__ be1,
    const float* __restrict__ W1, const float* __restrict__ b1,
    const float* __restrict__ g1, const float* __restrict__ bt1,
    const float* __restrict__ rm1, const float* __restrict__ rv1,
    const float* __restrict__ Wr, const float* __restrict__ br) {
    __shared__ float W1lds[D_IN * 64];
    __shared__ float Wrlds[D_IN * 64];
    __shared__ float u_lds[4][D_IN];
    __shared__ float x_lds[4][D_IN];
    const int t = threadIdx.x, w = t >> 6, c = t & 63;
    const int c15 = c & 15;
    for (int i = t; i < D_IN * 64; i += 256) {
        W1lds[i] = W1[i];
        Wrlds[i] = Wr[i];
    }
    h2vec we2 = {(_Float16)0.f, (_Float16)0.f};
    float bec = 0.f;
    if (c < D_IN) { we2[0] = (_Float16)We1[c]; we2[1] = (_Float16)We1[D_IN + c]; bec = be1[c]; }
    const float sj = g1[c] * rsqrtf(rv1[c] + BN_EPS);
    const float cj = (b1[c] - rm1[c]) * sj + bt1[c];
    const float brj = br[c];
    __syncthreads();

    const int n = blockIdx.x * 4 + w;
    const int rs = off[n], re = off[n + 1];
    float acc = 0.f;
    for (int base = rs; base < re; base += 64) {
        const int cnt = min(64, re - base);
        int2 rec = make_int2(0, 0);
        if (c < cnt) rec = edges[base + c];  // tail lanes (0,0) -> src 0 safe
        for (int j = 0; j < cnt; j += 16) {
            __half hv[16];
            int pkv[16];
#pragma unroll
            for (int u = 0; u < 16; ++u) {
                int s = __builtin_amdgcn_readlane(rec.x, j + u);
                pkv[u] = __builtin_amdgcn_readlane(rec.y, j + u);
                hv[u] = x16[(size_t)s * 16 + c15];  // unconditional, 1 line, 16 in flight
            }
#pragma unroll
            for (int u = 0; u < 16; ++u) {
                if (j + u < cnt) {
                    float q = __builtin_amdgcn_fdot2(__builtin_bit_cast(h2vec, pkv[u]), we2, bec, false);
                    acc += fmaxf(__half2float(hv[u]) + q, 0.f);  // lanes c>=16 garbage, discarded below
                }
            }
        }
    }
    if (c < D_IN) {
        float xc = x[(size_t)n * D_IN + c];
        x_lds[w][c] = xc;
        u_lds[w][c] = xc + acc;
    }
    float z = 0.f, r = 0.f;
#pragma unroll
    for (int k = 0; k < D_IN; ++k) {
        z = fmaf(u_lds[w][k], W1lds[k * 64 + c], z);
        r = fmaf(x_lds[w][k], Wrlds[k * 64 + c], r);
    }
    float v = fmaxf(fmaf(z, sj, cj), 0.f) + r + brj;
    hout[(size_t)n * 64 + c] = __float2half(v);
    hout8[(size_t)n * 64 + c] = f32_to_fp8(v);
}

// ---------------- Layers 2/3: fp8 neighbor gather (1 line/edge), fp16 center/epilogue ----------------
__global__ __launch_bounds__(256) void k_gine64(
    const __half* __restrict__ hin, const unsigned char* __restrict__ hin8,
    __half* __restrict__ hout, unsigned char* __restrict__ hout8,
    const int* __restrict__ off, const int2* __restrict__ edges,
    const float* __restrict__ We, const float* __restrict__ be,
    const float* __restrict__ W, const float* __restrict__ b,
    const float* __restrict__ g, const float* __restrict__ bt,
    const float* __restrict__ rm, const float* __restrict__ rv) {
    __shared__ _Float16 WtL[64][68];   // transposed W, fp16; 2-way aliasing free (m136)
    __shared__ _Float16 uL[4][64];
    const int t = threadIdx.x, w = t >> 6, c = t & 63;
    for (int i = t; i < 4096; i += 256) {
        int k = i >> 6, cc = i & 63;
        WtL[cc][k] = (_Float16)W[i];   // W[k*64+cc]
    }
    const _Float16 we0h = (_Float16)We[c], we1h = (_Float16)We[64 + c];
    const h2vec we2f = {we0h, we1h};
    const float becf = be[c];
    const float sj = g[c] * rsqrtf(rv[c] + BN_EPS);
    const float cj = (b[c] - rm[c]) * sj + bt[c];
    __syncthreads();

    const int wbase = (blockIdx.x * 4 + w) * NPW;
    for (int nn = 0; nn < NPW; ++nn) {
        const int n = wbase + nn;
        const int rs = off[n], re = off[n + 1];
        const __half hc16 = hin[(size_t)n * 64 + c];
        float acc = 0.f;
        for (int base = rs; base < re; base += 64) {
            const int cnt = min(64, re - base);
            int2 rec = make_int2(0, 0);
            if (c < cnt) rec = edges[base + c];  // tail lanes (0,0) -> src 0 safe
            for (int j = 0; j < cnt; j += 16) {
                int hvr[16];
#pragma unroll
                for (int u = 0; u < 16; ++u) {
                    int s = __builtin_amdgcn_readlane(rec.x, j + u);
                    hvr[u] = hin8[(size_t)s * 64 + c];  // 1 line/edge, 16 in flight
                }
#pragma unroll
                for (int u = 0; u < 16; ++u) {
                    if (j + u < cnt) {
                        int pk = __builtin_amdgcn_readlane(rec.y, j + u);
                        float q = __builtin_amdgcn_fdot2(__builtin_bit_cast(h2vec, pk), we2f, becf, false);
                        acc += fmaxf(fp8_to_f32(hvr[u]) + q, 0.f);
                    }
                }
            }
        }
        const float hc = __half2float(hc16);
        uL[w][c] = (_Float16)(hc + acc);
        float z = 0.f;
        const h4vec* u4p = (const h4vec*)uL[w];
        const h4vec* wt4p = (const h4vec*)&WtL[c][0];
#pragma unroll
        for (int k4 = 0; k4 < 16; ++k4) {
            h4vec uu = u4p[k4];
            h4vec ww = wt4p[k4];
            h2vec ul = __builtin_shufflevector(uu, uu, 0, 1);
            h2vec uh = __builtin_shufflevector(uu, uu, 2, 3);
            h2vec wl = __builtin_shufflevector(ww, ww, 0, 1);
            h2vec wh = __builtin_shufflevector(ww, ww, 2, 3);
            z = __builtin_amdgcn_fdot2(ul, wl, z, false);
            z = __builtin_amdgcn_fdot2(uh, wh, z, false);
        }
        float v = fmaxf(fmaf(z, sj, cj), 0.f) + hc;
        hout[(size_t)n * 64 + c] = __float2half(v);
        hout8[(size_t)n * 64 + c] = f32_to_fp8(v);
    }
}

// ---------------- Pool (mean+max per graph) + classifier ----------------
__global__ __launch_bounds__(256) void k_pool(
    const __half* __restrict__ h, const int* __restrict__ batch,
    const float* __restrict__ Wc1, const float* __restrict__ bc1,
    const float* __restrict__ Wc2, const float* __restrict__ bc2,
    float* __restrict__ out) {
    __shared__ float psum[4][64];
    __shared__ float pmax[4][64];
    __shared__ float pool[128];
    __shared__ float hid[64];
    const int t = threadIdx.x, w = t >> 6, c = t & 63;
    const int g = blockIdx.x;
    int lo = 0, hi = N_NODES;
    while (lo < hi) { int mid = (lo + hi) >> 1; if (batch[mid] < g) lo = mid + 1; else hi = mid; }
    int start = lo;
    hi = N_NODES;
    while (lo < hi) { int mid = (lo + hi) >> 1; if (batch[mid] < g + 1) lo = mid + 1; else hi = mid; }
    int end = lo;

    float s = 0.f, m = -3.4e38f;
    for (int i = start + w; i < end; i += 4) {
        float v = __half2float(h[(size_t)i * 64 + c]);
        s += v;
        m = fmaxf(m, v);
    }
    psum[w][c] = s;
    pmax[w][c] = m;
    __syncthreads();
    if (w == 0) {
        float ss = psum[0][c] + psum[1][c] + psum[2][c] + psum[3][c];
        float mm = fmaxf(fmaxf(pmax[0][c], pmax[1][c]), fmaxf(pmax[2][c], pmax[3][c]));
        int cnt = end - start;
        pool[c] = ss / fmaxf((float)cnt, 1.f);
        pool[64 + c] = (cnt > 0) ? mm : 0.f;
    }
    __syncthreads();
    if (t < 64) {
        float z = bc1[t];
#pragma unroll 8
        for (int k = 0; k < 128; ++k) z = fmaf(pool[k], Wc1[k * 64 + t], z);
        hid[t] = fmaxf(z, 0.f);
    }
    __syncthreads();
    if (t < N_CLS) {
        float z = bc2[t];
#pragma unroll
        for (int k = 0; k < 64; ++k) z = fmaf(hid[k], Wc2[k * N_CLS + t], z);
        out[g * N_CLS + t] = z;
    }
}

extern "C" void kernel_launch(void* const* d_in, const int* in_sizes, int n_in,
                              void* d_out, int out_size, void* d_ws, size_t ws_size,
                              hipStream_t stream) {
    const float* x     = (const float*)d_in[0];
    const int*   ei    = (const int*)d_in[1];
    const float* ea    = (const float*)d_in[2];
    const int*   batch = (const int*)d_in[3];
    const float* We1 = (const float*)d_in[4],  *be1 = (const float*)d_in[5];
    const float* We2 = (const float*)d_in[6],  *be2 = (const float*)d_in[7];
    const float* We3 = (const float*)d_in[8],  *be3 = (const float*)d_in[9];
    const float* W1 = (const float*)d_in[10], *b1 = (const float*)d_in[11];
    const float* g1 = (const float*)d_in[12], *bt1 = (const float*)d_in[13];
    const float* rm1 = (const float*)d_in[14], *rv1 = (const float*)d_in[15];
    const float* W2 = (const float*)d_in[16], *b2 = (const float*)d_in[17];
    const float* g2 = (const float*)d_in[18], *bt2 = (const float*)d_in[19];
    const float* rm2 = (const float*)d_in[20], *rv2 = (const float*)d_in[21];
    const float* W3 = (const float*)d_in[22], *b3 = (const float*)d_in[23];
    const float* g3 = (const float*)d_in[24], *bt3 = (const float*)d_in[25];
    const float* rm3 = (const float*)d_in[26], *rv3 = (const float*)d_in[27];
    const float* Wr = (const float*)d_in[28], *br = (const float*)d_in[29];
    const float* Wc1 = (const float*)d_in[30], *bc1 = (const float*)d_in[31];
    const float* Wc2 = (const float*)d_in[32], *bc2 = (const float*)d_in[33];

    int* off    = (int*)d_ws;                   // N+4
    int* gcount = off + (N_NODES + 4);          // 1024 (NB=1000, zero-padded)
    int* bbase  = gcount + 1024;                // 1024
    int2* edges = (int2*)(bbase + 1024);        // E * 8B packed records
    int2* stage = edges + E_EDGES;              // NB*BCAP * 8B fixed bucket regions
    __half* hA  = (__half*)(stage + (size_t)NB * BCAP);  // N*64 fp16
    __half* hB  = hA + (size_t)N_NODES * 64;    // N*64 fp16
    unsigned char* hA8 = (unsigned char*)(hB + (size_t)N_NODES * 64);  // N*64 fp8
    unsigned char* hB8 = hA8 + (size_t)N_NODES * 64;                   // N*64 fp8
    __half* x16 = (__half*)(hB8 + (size_t)N_NODES * 64);               // N*16 fp16

    hipMemsetAsync(gcount, 0, 1024 * sizeof(int), stream);

    const int* src = ei;
    const int* dst = ei + E_EDGES;

    k_pack_x<<<N_NODES * 16 / 256, 256, 0, stream>>>(x, x16);
    k_bin<<<E_EDGES / TILE, 256, 0, stream>>>(src, dst, (const float2*)ea, gcount, stage);
    k_bscan<<<1, 256, 0, stream>>>(gcount, bbase, off);
    k_final<<<NB, 256, 0, stream>>>(gcount, bbase, stage, off, edges);

    k_gine12<<<N_NODES / 4, 256, 0, stream>>>(x, x16, hA, hA8, off, edges,
                                              We1, be1, W1, b1, g1, bt1, rm1, rv1, Wr, br);
    const int g64_blocks = N_NODES / (4 * NPW);  // 4000
    k_gine64<<<g64_blocks, 256, 0, stream>>>(hA, hA8, hB, hB8, off, edges,
                                             We2, be2, W2, b2, g2, bt2, rm2, rv2);
    k_gine64<<<g64_blocks, 256, 0, stream>>>(hB, hB8, hA, hA8, off, edges,
                                             We3, be3, W3, b3, g3, bt3, rm3, rv3);
    k_pool<<<G_GRAPHS, 256, 0, stream>>>(hA, batch, Wc1, bc1, Wc2, bc2, (float*)d_out);
}

// Round 14
// 492.054 us; speedup vs baseline: 1.0699x; 1.0510x over previous
//
#include <hip/hip_runtime.h>
#include <hip/hip_bf16.h>
#include <hip/hip_fp16.h>

#define N_NODES 128000
#define E_EDGES 2048000
#define G_GRAPHS 512
#define D_IN 12
#define D_H 64
#define N_CLS 10
#define BN_EPS 1e-5f
#define NB 1000        // buckets = dst >> 7 (128-node ranges)
#define BCAP 2560      // fixed records per bucket region
#define TILE 8192      // edges per k_bin block (250 blocks) — 4096 shrank write runs, regressed
#define NPW 8          // nodes per wave in gine64
#define NPW12 4        // nodes per wave in gine12

typedef _Float16 h2vec __attribute__((ext_vector_type(2)));
typedef _Float16 h4vec __attribute__((ext_vector_type(4)));

__device__ __forceinline__ float fp8_to_f32(int b) {
    return __builtin_amdgcn_cvt_f32_fp8(b, 0);
}
__device__ __forceinline__ unsigned char f32_to_fp8(float v) {
    return (unsigned char)(__builtin_amdgcn_cvt_pk_fp8_f32(v, v, 0, false) & 0xff);
}

// ---------------- CSR build: bucket counting-sort ----------------

__global__ __launch_bounds__(256) void k_bin(const int* __restrict__ src, const int* __restrict__ dst,
                                             const float2* __restrict__ attr, int* __restrict__ gcount,
                                             int2* __restrict__ stage) {
    __shared__ int hist[NB];
    __shared__ int base_s[NB];
    __shared__ int rk[TILE];  // packed b(10)<<20 | dstLow(7)<<13 | rank(13)
    const int t = threadIdx.x;
    const int e0 = blockIdx.x * TILE;
    for (int i = t; i < NB; i += 256) hist[i] = 0;
    __syncthreads();
    for (int i = t; i < TILE; i += 256) {
        int d = dst[e0 + i];
        int b = d >> 7;
        int r = atomicAdd(&hist[b], 1);
        rk[i] = (b << 20) | ((d & 127) << 13) | r;
    }
    __syncthreads();
    for (int i = t; i < NB; i += 256) {
        int cb = hist[i];
        base_s[i] = i * BCAP + ((cb > 0) ? atomicAdd(&gcount[i], cb) : 0);
    }
    __syncthreads();
    for (int i = t; i < TILE; i += 256) {
        int pr = rk[i];
        int b = pr >> 20, dl = (pr >> 13) & 127, r = pr & 8191;
        float2 a = attr[e0 + i];
        __half2 h2 = __floats2half2_rn(a.x, a.y);
        stage[base_s[b] + r] = make_int2(src[e0 + i] | (dl << 17), *(int*)&h2);
    }
}

__global__ __launch_bounds__(256) void k_bscan(const int* __restrict__ gcount, int* __restrict__ bbase,
                                               int* __restrict__ offsets) {
    __shared__ int sm[256];
    const int t = threadIdx.x;
    int c0 = gcount[t * 4], c1 = gcount[t * 4 + 1], c2 = gcount[t * 4 + 2], c3 = gcount[t * 4 + 3];
    int s = c0 + c1 + c2 + c3;
    sm[t] = s;
    __syncthreads();
    for (int off = 1; off < 256; off <<= 1) {
        int x = 0;
        if (t >= off) x = sm[t - off];
        __syncthreads();
        sm[t] += x;
        __syncthreads();
    }
    int base = sm[t] - s;  // exclusive
    if (t * 4 < NB)     bbase[t * 4]     = base;
    if (t * 4 + 1 < NB) bbase[t * 4 + 1] = base + c0;
    if (t * 4 + 2 < NB) bbase[t * 4 + 2] = base + c0 + c1;
    if (t * 4 + 3 < NB) bbase[t * 4 + 3] = base + c0 + c1 + c2;
    if (t == 255) offsets[N_NODES] = sm[255];
}

__global__ __launch_bounds__(256) void k_final(const int* __restrict__ gcount, const int* __restrict__ bbase,
                                               const int2* __restrict__ stage,
                                               int* __restrict__ offsets, int2* __restrict__ edges) {
    __shared__ int2 recs[BCAP];   // 20.5 KB
    __shared__ int cnt[128];
    __shared__ int incl[128];
    const int b = blockIdx.x, t = threadIdx.x;
    const int count = gcount[b];
    const int base = bbase[b];
    if (t < 128) cnt[t] = 0;
    __syncthreads();
    for (int i = t; i < count; i += 256) {
        int2 r = stage[b * BCAP + i];
        recs[i] = r;
        atomicAdd(&cnt[(r.x >> 17) & 127], 1);
    }
    __syncthreads();
    if (t < 128) incl[t] = cnt[t];
    __syncthreads();
    for (int off = 1; off < 128; off <<= 1) {   // parallel Hillis-Steele over 128
        int x = 0;
        if (t >= off && t < 128) x = incl[t - off];
        __syncthreads();
        if (t < 128) incl[t] += x;
        __syncthreads();
    }
    if (t < 128) {
        int ex = incl[t] - cnt[t];
        offsets[b * 128 + t] = base + ex;
        cnt[t] = ex;   // becomes the placement cursor
    }
    __syncthreads();
    for (int i = t; i < count; i += 256) {
        int2 r = recs[i];
        int dl = (r.x >> 17) & 127;
        int p = atomicAdd(&cnt[dl], 1);
        edges[base + p] = make_int2(r.x & 0x1FFFF, r.y);
    }
}

// pack x [N,12] fp32 -> [N,16] fp16 (channels 12..15 = 0): 32B rows = 1 line/edge
__global__ __launch_bounds__(256) void k_pack_x(const float* __restrict__ x, __half* __restrict__ x16) {
    int idx = blockIdx.x * 256 + threadIdx.x;
    int n = idx >> 4, ch = idx & 15;
    x16[idx] = __float2half((ch < D_IN) ? x[n * D_IN + ch] : 0.f);
}

// ---------------- Layer 1 (12-dim input, 64-dim output; fp16+fp8 out) ----------------
__global__ __launch_bounds__(256) void k_gine12(
    const float* __restrict__ x, const __half* __restrict__ x16,
    __half* __restrict__ hout, unsigned char* __restrict__ hout8,
    const int* __restrict__ off, const int2* __restrict__ edges,
    const float* __restrict__ We1, const float* __restrict__ be1,
    const float* __restrict__ W1, const float* __restrict__ b1,
    const float* __restrict__ g1, const float* __restrict__ bt1,
    const float* __restrict__ rm1, const float* __restrict__ rv1,
    const float* __restrict__ Wr, const float* __restrict__ br) {
    __shared__ float W1lds[D_IN * 64];
    __shared__ float Wrlds[D_IN * 64];
    __shared__ float u_lds[4][D_IN];
    __shared__ float x_lds[4][D_IN];
    const int t = threadIdx.x, w = t >> 6, c = t & 63;
    const int c15 = c & 15;
    for (int i = t; i < D_IN * 64; i += 256) {
        W1lds[i] = W1[i];
        Wrlds[i] = Wr[i];
    }
    h2vec we2 = {(_Float16)0.f, (_Float16)0.f};
    float bec = 0.f;
    if (c < D_IN) { we2[0] = (_Float16)We1[c]; we2[1] = (_Float16)We1[D_IN + c]; bec = be1[c]; }
    const float sj = g1[c] * rsqrtf(rv1[c] + BN_EPS);
    const float cj = (b1[c] - rm1[c]) * sj + bt1[c];
    const float brj = br[c];
    __syncthreads();

    const int wbase = (blockIdx.x * 4 + w) * NPW12;
    for (int nn = 0; nn < NPW12; ++nn) {
        const int n = wbase + nn;
        const int rs = off[n], re = off[n + 1];
        float acc = 0.f;
        for (int base = rs; base < re; base += 64) {
            const int cnt = min(64, re - base);
            int2 rec = make_int2(0, 0);
            if (c < cnt) rec = edges[base + c];  // tail lanes (0,0) -> src 0 safe
            for (int j = 0; j < cnt; j += 16) {
                __half hv[16];
                int pkv[16];
#pragma unroll
                for (int u = 0; u < 16; ++u) {
                    int s = __builtin_amdgcn_readlane(rec.x, j + u);
                    pkv[u] = __builtin_amdgcn_readlane(rec.y, j + u);
                    hv[u] = x16[(size_t)s * 16 + c15];  // unconditional, 1 line, 16 in flight
                }
#pragma unroll
                for (int u = 0; u < 16; ++u) {
                    if (j + u < cnt) {
                        float q = __builtin_amdgcn_fdot2(__builtin_bit_cast(h2vec, pkv[u]), we2, bec, false);
                        acc += fmaxf(__half2float(hv[u]) + q, 0.f);  // lanes c>=16 garbage, discarded
                    }
                }
            }
        }
        if (c < D_IN) {
            float xc = x[(size_t)n * D_IN + c];
            x_lds[w][c] = xc;
            u_lds[w][c] = xc + acc;
        }
        float z = 0.f, r = 0.f;
#pragma unroll
        for (int k = 0; k < D_IN; ++k) {
            z = fmaf(u_lds[w][k], W1lds[k * 64 + c], z);
            r = fmaf(x_lds[w][k], Wrlds[k * 64 + c], r);
        }
        float v = fmaxf(fmaf(z, sj, cj), 0.f) + r + brj;
        hout[(size_t)n * 64 + c] = __float2half(v);
        hout8[(size_t)n * 64 + c] = f32_to_fp8(v);
    }
}

// ---------------- Layers 2/3: fp8 neighbor gather (1 line/edge), fp16 center/epilogue ----------------
__global__ __launch_bounds__(256) void k_gine64(
    const __half* __restrict__ hin, const unsigned char* __restrict__ hin8,
    __half* __restrict__ hout, unsigned char* __restrict__ hout8,
    const int* __restrict__ off, const int2* __restrict__ edges,
    const float* __restrict__ We, const float* __restrict__ be,
    const float* __restrict__ W, const float* __restrict__ b,
    const float* __restrict__ g, const float* __restrict__ bt,
    const float* __restrict__ rm, const float* __restrict__ rv) {
    __shared__ _Float16 WtL[64][68];   // transposed W, fp16; 2-way aliasing free (m136)
    __shared__ _Float16 uL[4][64];
    const int t = threadIdx.x, w = t >> 6, c = t & 63;
    for (int i = t; i < 4096; i += 256) {
        int k = i >> 6, cc = i & 63;
        WtL[cc][k] = (_Float16)W[i];   // W[k*64+cc]
    }
    const _Float16 we0h = (_Float16)We[c], we1h = (_Float16)We[64 + c];
    const h2vec we2f = {we0h, we1h};
    const float becf = be[c];
    const float sj = g[c] * rsqrtf(rv[c] + BN_EPS);
    const float cj = (b[c] - rm[c]) * sj + bt[c];
    __syncthreads();

    const int wbase = (blockIdx.x * 4 + w) * NPW;
    for (int nn = 0; nn < NPW; ++nn) {
        const int n = wbase + nn;
        const int rs = off[n], re = off[n + 1];
        const __half hc16 = hin[(size_t)n * 64 + c];
        float acc = 0.f;
        for (int base = rs; base < re; base += 64) {
            const int cnt = min(64, re - base);
            int2 rec = make_int2(0, 0);
            if (c < cnt) rec = edges[base + c];  // tail lanes (0,0) -> src 0 safe
            for (int j = 0; j < cnt; j += 16) {
                int hvr[16];
#pragma unroll
                for (int u = 0; u < 16; ++u) {
                    int s = __builtin_amdgcn_readlane(rec.x, j + u);
                    hvr[u] = hin8[(size_t)s * 64 + c];  // 1 line/edge, 16 in flight
                }
#pragma unroll
                for (int u = 0; u < 16; ++u) {
                    if (j + u < cnt) {
                        int pk = __builtin_amdgcn_readlane(rec.y, j + u);
                        float q = __builtin_amdgcn_fdot2(__builtin_bit_cast(h2vec, pk), we2f, becf, false);
                        acc += fmaxf(fp8_to_f32(hvr[u]) + q, 0.f);
                    }
                }
            }
        }
        const float hc = __half2float(hc16);
        uL[w][c] = (_Float16)(hc + acc);
        float z = 0.f;
        const h4vec* u4p = (const h4vec*)uL[w];
        const h4vec* wt4p = (const h4vec*)&WtL[c][0];
#pragma unroll
        for (int k4 = 0; k4 < 16; ++k4) {
            h4vec uu = u4p[k4];
            h4vec ww = wt4p[k4];
            h2vec ul = __builtin_shufflevector(uu, uu, 0, 1);
            h2vec uh = __builtin_shufflevector(uu, uu, 2, 3);
            h2vec wl = __builtin_shufflevector(ww, ww, 0, 1);
            h2vec wh = __builtin_shufflevector(ww, ww, 2, 3);
            z = __builtin_amdgcn_fdot2(ul, wl, z, false);
            z = __builtin_amdgcn_fdot2(uh, wh, z, false);
        }
        float v = fmaxf(fmaf(z, sj, cj), 0.f) + hc;
        hout[(size_t)n * 64 + c] = __float2half(v);
        hout8[(size_t)n * 64 + c] = f32_to_fp8(v);
    }
}

// ---------------- Pool (mean+max per graph) + classifier ----------------
__global__ __launch_bounds__(256) void k_pool(
    const __half* __restrict__ h, const int* __restrict__ batch,
    const float* __restrict__ Wc1, const float* __restrict__ bc1,
    const float* __restrict__ Wc2, const float* __restrict__ bc2,
    float* __restrict__ out) {
    __shared__ float psum[4][64];
    __shared__ float pmax[4][64];
    __shared__ float pool[128];
    __shared__ float hid[64];
    const int t = threadIdx.x, w = t >> 6, c = t & 63;
    const int g = blockIdx.x;
    int lo = 0, hi = N_NODES;
    while (lo < hi) { int mid = (lo + hi) >> 1; if (batch[mid] < g) lo = mid + 1; else hi = mid; }
    int start = lo;
    hi = N_NODES;
    while (lo < hi) { int mid = (lo + hi) >> 1; if (batch[mid] < g + 1) lo = mid + 1; else hi = mid; }
    int end = lo;

    float s = 0.f, m = -3.4e38f;
    for (int i = start + w; i < end; i += 4) {
        float v = __half2float(h[(size_t)i * 64 + c]);
        s += v;
        m = fmaxf(m, v);
    }
    psum[w][c] = s;
    pmax[w][c] = m;
    __syncthreads();
    if (w == 0) {
        float ss = psum[0][c] + psum[1][c] + psum[2][c] + psum[3][c];
        float mm = fmaxf(fmaxf(pmax[0][c], pmax[1][c]), fmaxf(pmax[2][c], pmax[3][c]));
        int cnt = end - start;
        pool[c] = ss / fmaxf((float)cnt, 1.f);
        pool[64 + c] = (cnt > 0) ? mm : 0.f;
    }
    __syncthreads();
    if (t < 64) {
        float z = bc1[t];
#pragma unroll 8
        for (int k = 0; k < 128; ++k) z = fmaf(pool[k], Wc1[k * 64 + t], z);
        hid[t] = fmaxf(z, 0.f);
    }
    __syncthreads();
    if (t < N_CLS) {
        float z = bc2[t];
#pragma unroll
        for (int k = 0; k < 64; ++k) z = fmaf(hid[k], Wc2[k * N_CLS + t], z);
        out[g * N_CLS + t] = z;
    }
}

extern "C" void kernel_launch(void* const* d_in, const int* in_sizes, int n_in,
                              void* d_out, int out_size, void* d_ws, size_t ws_size,
                              hipStream_t stream) {
    const float* x     = (const float*)d_in[0];
    const int*   ei    = (const int*)d_in[1];
    const float* ea    = (const float*)d_in[2];
    const int*   batch = (const int*)d_in[3];
    const float* We1 = (const float*)d_in[4],  *be1 = (const float*)d_in[5];
    const float* We2 = (const float*)d_in[6],  *be2 = (const float*)d_in[7];
    const float* We3 = (const float*)d_in[8],  *be3 = (const float*)d_in[9];
    const float* W1 = (const float*)d_in[10], *b1 = (const float*)d_in[11];
    const float* g1 = (const float*)d_in[12], *bt1 = (const float*)d_in[13];
    const float* rm1 = (const float*)d_in[14], *rv1 = (const float*)d_in[15];
    const float* W2 = (const float*)d_in[16], *b2 = (const float*)d_in[17];
    const float* g2 = (const float*)d_in[18], *bt2 = (const float*)d_in[19];
    const float* rm2 = (const float*)d_in[20], *rv2 = (const float*)d_in[21];
    const float* W3 = (const float*)d_in[22], *b3 = (const float*)d_in[23];
    const float* g3 = (const float*)d_in[24], *bt3 = (const float*)d_in[25];
    const float* rm3 = (const float*)d_in[26], *rv3 = (const float*)d_in[27];
    const float* Wr = (const float*)d_in[28], *br = (const float*)d_in[29];
    const float* Wc1 = (const float*)d_in[30], *bc1 = (const float*)d_in[31];
    const float* Wc2 = (const float*)d_in[32], *bc2 = (const float*)d_in[33];

    int* off    = (int*)d_ws;                   // N+4
    int* gcount = off + (N_NODES + 4);          // 1024 (NB=1000, zero-padded)
    int* bbase  = gcount + 1024;                // 1024
    int2* edges = (int2*)(bbase + 1024);        // E * 8B packed records
    int2* stage = edges + E_EDGES;              // NB*BCAP * 8B fixed bucket regions
    __half* hA  = (__half*)(stage + (size_t)NB * BCAP);  // N*64 fp16
    __half* hB  = hA + (size_t)N_NODES * 64;    // N*64 fp16
    unsigned char* hA8 = (unsigned char*)(hB + (size_t)N_NODES * 64);  // N*64 fp8
    unsigned char* hB8 = hA8 + (size_t)N_NODES * 64;                   // N*64 fp8
    __half* x16 = (__half*)(hB8 + (size_t)N_NODES * 64);               // N*16 fp16

    hipMemsetAsync(gcount, 0, 1024 * sizeof(int), stream);

    const int* src = ei;
    const int* dst = ei + E_EDGES;

    k_pack_x<<<N_NODES * 16 / 256, 256, 0, stream>>>(x, x16);
    k_bin<<<E_EDGES / TILE, 256, 0, stream>>>(src, dst, (const float2*)ea, gcount, stage);
    k_bscan<<<1, 256, 0, stream>>>(gcount, bbase, off);
    k_final<<<NB, 256, 0, stream>>>(gcount, bbase, stage, off, edges);

    k_gine12<<<N_NODES / (4 * NPW12), 256, 0, stream>>>(x, x16, hA, hA8, off, edges,
                                                        We1, be1, W1, b1, g1, bt1, rm1, rv1, Wr, br);
    const int g64_blocks = N_NODES / (4 * NPW);  // 4000
    k_gine64<<<g64_blocks, 256, 0, stream>>>(hA, hA8, hB, hB8, off, edges,
                                             We2, be2, W2, b2, g2, bt2, rm2, rv2);
    k_gine64<<<g64_blocks, 256, 0, stream>>>(hB, hB8, hA, hA8, off, edges,
                                             We3, be3, W3, b3, g3, bt3, rm3, rv3);
    k_pool<<<G_GRAPHS, 256, 0, stream>>>(hA, batch, Wc1, bc1, Wc2, bc2, (float*)d_out);
}